// Round 1
// baseline (638.396 us; speedup 1.0000x reference)
//
#include <hip/hip_runtime.h>

#define N_NODES 100000
#define N_EDGES 1600000
#define F 128

// ---------------- CSR build ----------------

__global__ void hist_kernel(const int* __restrict__ rows, int* __restrict__ deg) {
    int i = blockIdx.x * blockDim.x + threadIdx.x;
    if (i < N_EDGES) atomicAdd(&deg[rows[i]], 1);
}

#define SCAN_B 1024
__global__ __launch_bounds__(SCAN_B) void scan_block_kernel(const int* __restrict__ deg,
                                                            int* __restrict__ inc,
                                                            int* __restrict__ bsum) {
    __shared__ int s[SCAN_B];
    int t = threadIdx.x;
    int g = blockIdx.x * SCAN_B + t;
    int v = (g < N_NODES) ? deg[g] : 0;
    s[t] = v;
    __syncthreads();
    // Hillis-Steele inclusive scan (read, barrier, write, barrier)
    for (int off = 1; off < SCAN_B; off <<= 1) {
        int x = (t >= off) ? s[t - off] : 0;
        __syncthreads();
        s[t] += x;
        __syncthreads();
    }
    if (g < N_NODES) inc[g] = s[t];
    if (t == SCAN_B - 1) bsum[blockIdx.x] = s[t];
}

__global__ void scan_bsum_kernel(const int* __restrict__ bsum, int* __restrict__ boff, int nb) {
    if (threadIdx.x == 0 && blockIdx.x == 0) {
        int run = 0;
        for (int i = 0; i < nb; ++i) { boff[i] = run; run += bsum[i]; }
    }
}

__global__ void finalize_kernel(const int* __restrict__ deg, const int* __restrict__ inc,
                                const int* __restrict__ boff, int* __restrict__ row_start,
                                int* __restrict__ cursor) {
    int g = blockIdx.x * blockDim.x + threadIdx.x;
    if (g < N_NODES) {
        int rs = inc[g] - deg[g] + boff[g / SCAN_B];  // exclusive scan value
        row_start[g] = rs;
        cursor[g] = rs;
    }
    if (g == 0) row_start[N_NODES] = N_EDGES;
}

__global__ void scatter_kernel(const int* __restrict__ rows, const int* __restrict__ cols,
                               const float* __restrict__ vals, int* __restrict__ cursor,
                               int* __restrict__ csr_col, float* __restrict__ csr_val) {
    int i = blockIdx.x * blockDim.x + threadIdx.x;
    if (i < N_EDGES) {
        int p = atomicAdd(&cursor[rows[i]], 1);
        csr_col[p] = cols[i];
        csr_val[p] = vals[i];
    }
}

// ---------------- Dense GEMM: T[r][c] = sum_k X[r][k] * W[k][c] ----------------
// 32 rows per block, full 128 cols. W (64KB) + X tile (16KB) in LDS.
#define TILE_R 32
__global__ __launch_bounds__(256) void gemm128_kernel(const float* __restrict__ X,
                                                      const float* __restrict__ W,
                                                      float* __restrict__ T) {
    __shared__ float ws[128 * 128];     // 64 KB
    __shared__ float xs[TILE_R * 128];  // 16 KB
    int tid = threadIdx.x;

    // stage W: 16384 floats = 4096 float4 / 256 threads = 16 each
    const float4* W4 = (const float4*)W;
    float4* ws4 = (float4*)ws;
#pragma unroll
    for (int i = 0; i < 16; ++i) ws4[tid + 256 * i] = W4[tid + 256 * i];

    // stage X tile: 32*128 floats = 1024 float4 / 256 threads = 4 each
    long r0 = (long)blockIdx.x * TILE_R;
    const float4* X4 = (const float4*)(X + r0 * 128);
    float4* xs4 = (float4*)xs;
#pragma unroll
    for (int i = 0; i < 4; ++i) xs4[tid + 256 * i] = X4[tid + 256 * i];
    __syncthreads();

    int tx = tid & 31;   // col group: 4 consecutive cols
    int ty = tid >> 5;   // 0..7 -> 4 rows each
    int c = tx * 4;
    float acc[4][4] = {};
#pragma unroll 4
    for (int k = 0; k < 128; ++k) {
        float4 w = *(const float4*)&ws[k * 128 + c];
#pragma unroll
        for (int i = 0; i < 4; ++i) {
            float x = xs[(ty * 4 + i) * 128 + k];
            acc[i][0] += x * w.x;
            acc[i][1] += x * w.y;
            acc[i][2] += x * w.z;
            acc[i][3] += x * w.w;
        }
    }
#pragma unroll
    for (int i = 0; i < 4; ++i) {
        long r = r0 + ty * 4 + i;
        *(float4*)&T[r * 128 + c] =
            make_float4(acc[i][0], acc[i][1], acc[i][2], acc[i][3]);
    }
}

// ---------------- SpMM (CSR) + fused ReLU ----------------
// One wave per row; lane handles 2 features (float2). out[row] = relu(sum val * T[col]).
__global__ __launch_bounds__(256) void spmm_relu_kernel(const int* __restrict__ row_start,
                                                        const int* __restrict__ csr_col,
                                                        const float* __restrict__ csr_val,
                                                        const float* __restrict__ T,
                                                        float* __restrict__ out) {
    int wave = threadIdx.x >> 6;
    int lane = threadIdx.x & 63;
    int row = blockIdx.x * 4 + wave;
    int s = row_start[row];
    int e = row_start[row + 1];
    float ax = 0.f, ay = 0.f;
    for (int p = s; p < e; ++p) {
        int col = csr_col[p];
        float v = csr_val[p];
        const float2 x = *(const float2*)&T[col * 128 + lane * 2];
        ax += v * x.x;
        ay += v * x.y;
    }
    float2* o = (float2*)&out[row * 128 + lane * 2];
    *o = make_float2(fmaxf(ax, 0.f), fmaxf(ay, 0.f));
}

// ---------------- launch ----------------
extern "C" void kernel_launch(void* const* d_in, const int* in_sizes, int n_in,
                              void* d_out, int out_size, void* d_ws, size_t ws_size,
                              hipStream_t stream) {
    const float* X     = (const float*)d_in[0];  // [N,128]
    const float* evals = (const float*)d_in[1];  // [E]
    const float* W0    = (const float*)d_in[2];  // [128,128]
    const float* W1    = (const float*)d_in[3];  // [128,128]
    const int* erows   = (const int*)d_in[4];    // [E]
    const int* ecols   = (const int*)d_in[5];    // [E]
    float* out = (float*)d_out;                  // [N,128]

    // ---- workspace carve (aligned to 256B) ----
    char* ws = (char*)d_ws;
    size_t off = 0;
    auto carve = [&](size_t bytes) {
        char* p = ws + off;
        off += (bytes + 255) & ~(size_t)255;
        return p;
    };
    float* T        = (float*)carve((size_t)N_NODES * F * 4);  // 51.2 MB
    float* H        = (float*)carve((size_t)N_NODES * F * 4);  // 51.2 MB
    int*   deg      = (int*)carve((size_t)N_NODES * 4);
    int*   inc      = (int*)carve((size_t)N_NODES * 4);
    int*   row_start= (int*)carve((size_t)(N_NODES + 1) * 4);
    int*   cursor   = (int*)carve((size_t)N_NODES * 4);
    int*   bsum     = (int*)carve(4096);
    int*   boff     = (int*)carve(4096);
    int*   csr_col  = (int*)carve((size_t)N_EDGES * 4);
    float* csr_val  = (float*)carve((size_t)N_EDGES * 4);
    (void)ws_size; (void)in_sizes; (void)n_in; (void)out_size;

    int nb_scan = (N_NODES + SCAN_B - 1) / SCAN_B;  // 98

    // ---- CSR build ----
    hipMemsetAsync(deg, 0, (size_t)N_NODES * 4, stream);
    hist_kernel<<<(N_EDGES + 255) / 256, 256, 0, stream>>>(erows, deg);
    scan_block_kernel<<<nb_scan, SCAN_B, 0, stream>>>(deg, inc, bsum);
    scan_bsum_kernel<<<1, 64, 0, stream>>>(bsum, boff, nb_scan);
    finalize_kernel<<<(N_NODES + 255) / 256, 256, 0, stream>>>(deg, inc, boff, row_start, cursor);
    scatter_kernel<<<(N_EDGES + 255) / 256, 256, 0, stream>>>(erows, ecols, evals, cursor,
                                                              csr_col, csr_val);

    // ---- layer 0: H = relu(Ahat @ (X @ W0)) ----
    gemm128_kernel<<<N_NODES / TILE_R, 256, 0, stream>>>(X, W0, T);
    spmm_relu_kernel<<<N_NODES / 4, 256, 0, stream>>>(row_start, csr_col, csr_val, T, H);

    // ---- layer 1: out = relu(Ahat @ (H @ W1)) ----
    gemm128_kernel<<<N_NODES / TILE_R, 256, 0, stream>>>(H, W1, T);
    spmm_relu_kernel<<<N_NODES / 4, 256, 0, stream>>>(row_start, csr_col, csr_val, T, out);
}

// Round 2
// 433.268 us; speedup vs baseline: 1.4734x; 1.4734x over previous
//
#include <hip/hip_runtime.h>

#define N_NODES 100000
#define N_EDGES 1600000
#define F 128

__device__ __forceinline__ float bf_lo(unsigned int u) { return __uint_as_float(u << 16); }
__device__ __forceinline__ float bf_hi(unsigned int u) { return __uint_as_float(u & 0xffff0000u); }
__device__ __forceinline__ unsigned short f2bf(float f) {
    unsigned int u = __float_as_uint(f);
    u += 0x7fffu + ((u >> 16) & 1u);   // round-to-nearest-even
    return (unsigned short)(u >> 16);
}

// ---------------- CSR build ----------------

__global__ void hist_kernel(const int* __restrict__ rows, int* __restrict__ deg) {
    int i = blockIdx.x * blockDim.x + threadIdx.x;
    if (i < N_EDGES) atomicAdd(&deg[rows[i]], 1);
}

#define SCAN_B 1024
__global__ __launch_bounds__(SCAN_B) void scan_block_kernel(const int* __restrict__ deg,
                                                            int* __restrict__ inc,
                                                            int* __restrict__ bsum) {
    __shared__ int s[SCAN_B];
    int t = threadIdx.x;
    int g = blockIdx.x * SCAN_B + t;
    int v = (g < N_NODES) ? deg[g] : 0;
    s[t] = v;
    __syncthreads();
    for (int off = 1; off < SCAN_B; off <<= 1) {
        int x = (t >= off) ? s[t - off] : 0;
        __syncthreads();
        s[t] += x;
        __syncthreads();
    }
    if (g < N_NODES) inc[g] = s[t];
    if (t == SCAN_B - 1) bsum[blockIdx.x] = s[t];
}

// parallel scan of the (<=128) block sums — replaces the serial 1-thread loop
__global__ __launch_bounds__(128) void scan_bsum_kernel(const int* __restrict__ bsum,
                                                        int* __restrict__ boff, int nb) {
    __shared__ int s[128];
    int t = threadIdx.x;
    int v = (t < nb) ? bsum[t] : 0;
    s[t] = v;
    __syncthreads();
    for (int off = 1; off < 128; off <<= 1) {
        int x = (t >= off) ? s[t - off] : 0;
        __syncthreads();
        s[t] += x;
        __syncthreads();
    }
    if (t < nb) boff[t] = s[t] - v;  // exclusive
}

__global__ void finalize_kernel(const int* __restrict__ deg, const int* __restrict__ inc,
                                const int* __restrict__ boff, int* __restrict__ row_start,
                                int* __restrict__ cursor) {
    int g = blockIdx.x * blockDim.x + threadIdx.x;
    if (g < N_NODES) {
        int rs = inc[g] - deg[g] + boff[g / SCAN_B];
        row_start[g] = rs;
        cursor[g] = rs;
    }
    if (g == 0) row_start[N_NODES] = N_EDGES;
}

__global__ void scatter_kernel(const int* __restrict__ rows, const int* __restrict__ cols,
                               const float* __restrict__ vals, int* __restrict__ cursor,
                               int* __restrict__ csr_col, float* __restrict__ csr_val) {
    int i = blockIdx.x * blockDim.x + threadIdx.x;
    if (i < N_EDGES) {
        int p = atomicAdd(&cursor[rows[i]], 1);
        csr_col[p] = cols[i];
        csr_val[p] = vals[i];
    }
}

// ---------------- Dense GEMM: T[r][c] = sum_k X[r][k] * W[k][c], output bf16 ----------------
// 32 rows/block, full 128 cols. W fp32 (64KB) + X tile (16KB fp32 / staged-converted bf16) in LDS.
#define TILE_R 32
template <bool IN_BF16>
__global__ __launch_bounds__(256) void gemm128_kernel(const void* __restrict__ Xv,
                                                      const float* __restrict__ W,
                                                      unsigned short* __restrict__ T) {
    __shared__ float ws[128 * 128];     // 64 KB
    __shared__ float xs[TILE_R * 128];  // 16 KB
    int tid = threadIdx.x;

    const float4* W4 = (const float4*)W;
    float4* ws4 = (float4*)ws;
#pragma unroll
    for (int i = 0; i < 16; ++i) ws4[tid + 256 * i] = W4[tid + 256 * i];

    long r0 = (long)blockIdx.x * TILE_R;
    if constexpr (IN_BF16) {
        const uint4* X4 = (const uint4*)((const unsigned short*)Xv + r0 * 128);
#pragma unroll
        for (int i = 0; i < 2; ++i) {
            int li = tid + 256 * i;          // uint4 index; holds 8 bf16
            uint4 u = X4[li];
            float* d = &xs[li * 8];
            d[0] = bf_lo(u.x); d[1] = bf_hi(u.x);
            d[2] = bf_lo(u.y); d[3] = bf_hi(u.y);
            d[4] = bf_lo(u.z); d[5] = bf_hi(u.z);
            d[6] = bf_lo(u.w); d[7] = bf_hi(u.w);
        }
    } else {
        const float4* X4 = (const float4*)((const float*)Xv + r0 * 128);
        float4* xs4 = (float4*)xs;
#pragma unroll
        for (int i = 0; i < 4; ++i) xs4[tid + 256 * i] = X4[tid + 256 * i];
    }
    __syncthreads();

    int tx = tid & 31;   // col group: 4 consecutive cols
    int ty = tid >> 5;   // 0..7 -> 4 rows each
    int c = tx * 4;
    float acc[4][4] = {};
#pragma unroll 4
    for (int k = 0; k < 128; ++k) {
        float4 w = *(const float4*)&ws[k * 128 + c];
#pragma unroll
        for (int i = 0; i < 4; ++i) {
            float x = xs[(ty * 4 + i) * 128 + k];
            acc[i][0] = fmaf(x, w.x, acc[i][0]);
            acc[i][1] = fmaf(x, w.y, acc[i][1]);
            acc[i][2] = fmaf(x, w.z, acc[i][2]);
            acc[i][3] = fmaf(x, w.w, acc[i][3]);
        }
    }
#pragma unroll
    for (int i = 0; i < 4; ++i) {
        long r = r0 + ty * 4 + i;
        ushort4 o;
        o.x = f2bf(acc[i][0]); o.y = f2bf(acc[i][1]);
        o.z = f2bf(acc[i][2]); o.w = f2bf(acc[i][3]);
        *(ushort4*)&T[r * 128 + c] = o;
    }
}

// ---------------- SpMM (CSR, bf16 gather operand) + fused ReLU ----------------
// One wave per row; lane covers 2 features (one uint = 2 bf16). fp32 accumulate.
// csr_col/val loaded coalesced per-lane, broadcast via shfl. Gather loop unrolled x4.
template <bool OUT_BF16>
__global__ __launch_bounds__(256) void spmm_relu_kernel(const int* __restrict__ row_start,
                                                        const int* __restrict__ csr_col,
                                                        const float* __restrict__ csr_val,
                                                        const unsigned int* __restrict__ Tu,
                                                        void* __restrict__ outv) {
    int wave = threadIdx.x >> 6;
    int lane = threadIdx.x & 63;
    int row = blockIdx.x * 4 + wave;
    int s = row_start[row];
    int e = row_start[row + 1];
    float ax = 0.f, ay = 0.f;
    for (int base = s; base < e; base += 64) {
        int cnt = min(64, e - base);
        int col_l = 0; float val_l = 0.f;
        if (lane < cnt) { col_l = csr_col[base + lane]; val_l = csr_val[base + lane]; }
        int j = 0;
        for (; j + 4 <= cnt; j += 4) {
            int   c0 = __shfl(col_l, j),     c1 = __shfl(col_l, j + 1);
            int   c2 = __shfl(col_l, j + 2), c3 = __shfl(col_l, j + 3);
            float v0 = __shfl(val_l, j),     v1 = __shfl(val_l, j + 1);
            float v2 = __shfl(val_l, j + 2), v3 = __shfl(val_l, j + 3);
            unsigned int x0 = Tu[c0 * 64 + lane];
            unsigned int x1 = Tu[c1 * 64 + lane];
            unsigned int x2 = Tu[c2 * 64 + lane];
            unsigned int x3 = Tu[c3 * 64 + lane];
            ax = fmaf(v0, bf_lo(x0), ax); ay = fmaf(v0, bf_hi(x0), ay);
            ax = fmaf(v1, bf_lo(x1), ax); ay = fmaf(v1, bf_hi(x1), ay);
            ax = fmaf(v2, bf_lo(x2), ax); ay = fmaf(v2, bf_hi(x2), ay);
            ax = fmaf(v3, bf_lo(x3), ax); ay = fmaf(v3, bf_hi(x3), ay);
        }
        for (; j < cnt; ++j) {
            int   c = __shfl(col_l, j);
            float v = __shfl(val_l, j);
            unsigned int x = Tu[c * 64 + lane];
            ax = fmaf(v, bf_lo(x), ax); ay = fmaf(v, bf_hi(x), ay);
        }
    }
    ax = fmaxf(ax, 0.f);
    ay = fmaxf(ay, 0.f);
    if constexpr (OUT_BF16) {
        unsigned int* o = (unsigned int*)outv;
        o[row * 64 + lane] = (unsigned int)f2bf(ax) | ((unsigned int)f2bf(ay) << 16);
    } else {
        float2* o = (float2*)((float*)outv + row * 128 + lane * 2);
        *o = make_float2(ax, ay);
    }
}

// ---------------- launch ----------------
extern "C" void kernel_launch(void* const* d_in, const int* in_sizes, int n_in,
                              void* d_out, int out_size, void* d_ws, size_t ws_size,
                              hipStream_t stream) {
    const float* X     = (const float*)d_in[0];  // [N,128] fp32
    const float* evals = (const float*)d_in[1];  // [E]
    const float* W0    = (const float*)d_in[2];  // [128,128]
    const float* W1    = (const float*)d_in[3];  // [128,128]
    const int* erows   = (const int*)d_in[4];    // [E]
    const int* ecols   = (const int*)d_in[5];    // [E]
    float* out = (float*)d_out;                  // [N,128] fp32

    char* ws = (char*)d_ws;
    size_t off = 0;
    auto carve = [&](size_t bytes) {
        char* p = ws + off;
        off += (bytes + 255) & ~(size_t)255;
        return p;
    };
    unsigned short* T = (unsigned short*)carve((size_t)N_NODES * F * 2);  // 25.6 MB bf16
    unsigned short* H = (unsigned short*)carve((size_t)N_NODES * F * 2);  // 25.6 MB bf16
    int*   deg       = (int*)carve((size_t)N_NODES * 4);
    int*   inc       = (int*)carve((size_t)N_NODES * 4);
    int*   row_start = (int*)carve((size_t)(N_NODES + 1) * 4);
    int*   cursor    = (int*)carve((size_t)N_NODES * 4);
    int*   bsum      = (int*)carve(4096);
    int*   boff      = (int*)carve(4096);
    int*   csr_col   = (int*)carve((size_t)N_EDGES * 4);
    float* csr_val   = (float*)carve((size_t)N_EDGES * 4);
    (void)ws_size; (void)in_sizes; (void)n_in; (void)out_size;

    int nb_scan = (N_NODES + SCAN_B - 1) / SCAN_B;  // 98

    // ---- CSR build ----
    hipMemsetAsync(deg, 0, (size_t)N_NODES * 4, stream);
    hist_kernel<<<(N_EDGES + 255) / 256, 256, 0, stream>>>(erows, deg);
    scan_block_kernel<<<nb_scan, SCAN_B, 0, stream>>>(deg, inc, bsum);
    scan_bsum_kernel<<<1, 128, 0, stream>>>(bsum, boff, nb_scan);
    finalize_kernel<<<(N_NODES + 255) / 256, 256, 0, stream>>>(deg, inc, boff, row_start, cursor);
    scatter_kernel<<<(N_EDGES + 255) / 256, 256, 0, stream>>>(erows, ecols, evals, cursor,
                                                              csr_col, csr_val);

    // ---- layer 0: H = relu(Ahat @ (X @ W0)) ----
    gemm128_kernel<false><<<N_NODES / TILE_R, 256, 0, stream>>>(X, W0, T);
    spmm_relu_kernel<true><<<N_NODES / 4, 256, 0, stream>>>(row_start, csr_col, csr_val,
                                                            (const unsigned int*)T, H);

    // ---- layer 1: out = relu(Ahat @ (H @ W1)) ----
    gemm128_kernel<true><<<N_NODES / TILE_R, 256, 0, stream>>>(H, W1, T);
    spmm_relu_kernel<false><<<N_NODES / 4, 256, 0, stream>>>(row_start, csr_col, csr_val,
                                                             (const unsigned int*)T, out);
}

// Round 3
// 287.926 us; speedup vs baseline: 2.2172x; 1.5048x over previous
//
#include <hip/hip_runtime.h>

#define N_NODES 100000
#define N_EDGES 1600000
#define F 128

#define BUCKET_BITS 9
#define BUCKET_SIZE 512                              // rows per bucket
#define NBUCKETS ((N_NODES + BUCKET_SIZE - 1) / BUCKET_SIZE)  // 196
#define EPB_A 8192                                   // edges per block, pass A
#define ABLOCKS ((N_EDGES + EPB_A - 1) / EPB_A)      // 196

__device__ __forceinline__ float bf_lo(unsigned int u) { return __uint_as_float(u << 16); }
__device__ __forceinline__ float bf_hi(unsigned int u) { return __uint_as_float(u & 0xffff0000u); }
__device__ __forceinline__ unsigned short f2bf(float f) {
    unsigned int u = __float_as_uint(f);
    u += 0x7fffu + ((u >> 16) & 1u);   // round-to-nearest-even
    return (unsigned short)(u >> 16);
}

// ---------------- CSR build: two-level counting sort ----------------

// global bucket histogram (LDS-aggregated)
__global__ __launch_bounds__(256) void bhist_kernel(const int* __restrict__ rows,
                                                    int* __restrict__ ghist) {
    __shared__ int hist[NBUCKETS];
    int tid = threadIdx.x;
    int start = blockIdx.x * EPB_A;
    int cnt = min(EPB_A, N_EDGES - start);
    for (int i = tid; i < NBUCKETS; i += 256) hist[i] = 0;
    __syncthreads();
    for (int i = tid; i < cnt; i += 256) atomicAdd(&hist[rows[start + i] >> BUCKET_BITS], 1);
    __syncthreads();
    for (int i = tid; i < NBUCKETS; i += 256)
        if (hist[i]) atomicAdd(&ghist[i], hist[i]);
}

// exclusive scan of the 196 bucket counts
__global__ __launch_bounds__(256) void bscan_kernel(const int* __restrict__ ghist,
                                                    int* __restrict__ bucket_start,
                                                    int* __restrict__ bucket_cursor) {
    __shared__ int s[256];
    int t = threadIdx.x;
    int v = (t < NBUCKETS) ? ghist[t] : 0;
    s[t] = v;
    __syncthreads();
    for (int off = 1; off < 256; off <<= 1) {
        int x = (t >= off) ? s[t - off] : 0;
        __syncthreads();
        s[t] += x;
        __syncthreads();
    }
    if (t < NBUCKETS) {
        int ex = s[t] - v;
        bucket_start[t] = ex;
        bucket_cursor[t] = ex;
    }
    if (t == NBUCKETS - 1) bucket_start[NBUCKETS] = s[t];  // == E
}

// pass A: bin edges by bucket, chunk-reserved contiguous writes
__global__ __launch_bounds__(256) void binA_kernel(const int* __restrict__ rows,
                                                   const int* __restrict__ cols,
                                                   const float* __restrict__ vals,
                                                   int* __restrict__ bucket_cursor,
                                                   uint2* __restrict__ stage) {
    __shared__ int hist[NBUCKETS];
    __shared__ int base[NBUCKETS];
    int tid = threadIdx.x;
    int start = blockIdx.x * EPB_A;
    int cnt = min(EPB_A, N_EDGES - start);
    for (int i = tid; i < NBUCKETS; i += 256) hist[i] = 0;
    __syncthreads();
    for (int i = tid; i < cnt; i += 256) atomicAdd(&hist[rows[start + i] >> BUCKET_BITS], 1);
    __syncthreads();
    for (int i = tid; i < NBUCKETS; i += 256) {
        int h = hist[i];
        base[i] = h ? atomicAdd(&bucket_cursor[i], h) : 0;
        hist[i] = 0;  // reuse as running in-block cursor
    }
    __syncthreads();
    for (int i = tid; i < cnt; i += 256) {
        int r = rows[start + i];
        int c = cols[start + i];
        unsigned vb = __float_as_uint(vals[start + i]);
        int b = r >> BUCKET_BITS;
        int p = base[b] + atomicAdd(&hist[b], 1);
        stage[p] = make_uint2(((unsigned)(r & (BUCKET_SIZE - 1)) << 17) | (unsigned)c, vb);
    }
}

// pass B: per-bucket sort by row -> final CSR (packed col|val) + row_start
__global__ __launch_bounds__(1024) void binB_kernel(const uint2* __restrict__ stage,
                                                    const int* __restrict__ bucket_start,
                                                    uint2* __restrict__ csr,
                                                    int* __restrict__ row_start) {
    __shared__ int hist[BUCKET_SIZE];
    __shared__ int scanv[BUCKET_SIZE];
    __shared__ int cur[BUCKET_SIZE];
    int b = blockIdx.x;
    int t = threadIdx.x;
    int s0 = bucket_start[b];
    int cnt = bucket_start[b + 1] - s0;
    if (t < BUCKET_SIZE) hist[t] = 0;
    __syncthreads();
    for (int i = t; i < cnt; i += 1024) atomicAdd(&hist[stage[s0 + i].x >> 17], 1);
    __syncthreads();
    if (t < BUCKET_SIZE) scanv[t] = hist[t];
    __syncthreads();
    for (int off = 1; off < BUCKET_SIZE; off <<= 1) {
        int x = 0;
        if (t < BUCKET_SIZE && t >= off) x = scanv[t - off];
        __syncthreads();
        if (t < BUCKET_SIZE) scanv[t] += x;
        __syncthreads();
    }
    if (t < BUCKET_SIZE) {
        int ex = s0 + scanv[t] - hist[t];  // global exclusive offset for this row
        cur[t] = ex;
        int row = (b << BUCKET_BITS) + t;
        if (row < N_NODES) row_start[row] = ex;
    }
    if (b == 0 && t == 0) row_start[N_NODES] = N_EDGES;
    __syncthreads();
    for (int i = t; i < cnt; i += 1024) {
        uint2 e = stage[s0 + i];
        int p = atomicAdd(&cur[e.x >> 17], 1);
        csr[p] = make_uint2(e.x & 0x1FFFFu, e.y);
    }
}

// ---------------- Dense GEMM: T[r][c] = sum_k X[r][k] * W[k][c], output bf16 ----------------
#define TILE_R 32
template <bool IN_BF16>
__global__ __launch_bounds__(256) void gemm128_kernel(const void* __restrict__ Xv,
                                                      const float* __restrict__ W,
                                                      unsigned short* __restrict__ T) {
    __shared__ float ws[128 * 128];     // 64 KB
    __shared__ float xs[TILE_R * 128];  // 16 KB
    int tid = threadIdx.x;

    const float4* W4 = (const float4*)W;
    float4* ws4 = (float4*)ws;
#pragma unroll
    for (int i = 0; i < 16; ++i) ws4[tid + 256 * i] = W4[tid + 256 * i];

    long r0 = (long)blockIdx.x * TILE_R;
    if constexpr (IN_BF16) {
        const uint4* X4 = (const uint4*)((const unsigned short*)Xv + r0 * 128);
#pragma unroll
        for (int i = 0; i < 2; ++i) {
            int li = tid + 256 * i;          // uint4 index; holds 8 bf16
            uint4 u = X4[li];
            float* d = &xs[li * 8];
            d[0] = bf_lo(u.x); d[1] = bf_hi(u.x);
            d[2] = bf_lo(u.y); d[3] = bf_hi(u.y);
            d[4] = bf_lo(u.z); d[5] = bf_hi(u.z);
            d[6] = bf_lo(u.w); d[7] = bf_hi(u.w);
        }
    } else {
        const float4* X4 = (const float4*)((const float*)Xv + r0 * 128);
        float4* xs4 = (float4*)xs;
#pragma unroll
        for (int i = 0; i < 4; ++i) xs4[tid + 256 * i] = X4[tid + 256 * i];
    }
    __syncthreads();

    int tx = tid & 31;   // col group: 4 consecutive cols
    int ty = tid >> 5;   // 0..7 -> 4 rows each
    int c = tx * 4;
    float acc[4][4] = {};
#pragma unroll 4
    for (int k = 0; k < 128; ++k) {
        float4 w = *(const float4*)&ws[k * 128 + c];
#pragma unroll
        for (int i = 0; i < 4; ++i) {
            float x = xs[(ty * 4 + i) * 128 + k];
            acc[i][0] = fmaf(x, w.x, acc[i][0]);
            acc[i][1] = fmaf(x, w.y, acc[i][1]);
            acc[i][2] = fmaf(x, w.z, acc[i][2]);
            acc[i][3] = fmaf(x, w.w, acc[i][3]);
        }
    }
#pragma unroll
    for (int i = 0; i < 4; ++i) {
        long r = r0 + ty * 4 + i;
        ushort4 o;
        o.x = f2bf(acc[i][0]); o.y = f2bf(acc[i][1]);
        o.z = f2bf(acc[i][2]); o.w = f2bf(acc[i][3]);
        *(ushort4*)&T[r * 128 + c] = o;
    }
}

// ---------------- SpMM (CSR packed, bf16 gather operand) + fused ReLU ----------------
template <bool OUT_BF16>
__global__ __launch_bounds__(256) void spmm_relu_kernel(const int* __restrict__ row_start,
                                                        const uint2* __restrict__ csr,
                                                        const unsigned int* __restrict__ Tu,
                                                        void* __restrict__ outv) {
    int wave = threadIdx.x >> 6;
    int lane = threadIdx.x & 63;
    int row = blockIdx.x * 4 + wave;
    int s = row_start[row];
    int e = row_start[row + 1];
    float ax = 0.f, ay = 0.f;
    for (int base = s; base < e; base += 64) {
        int cnt = min(64, e - base);
        int col_l = 0; float val_l = 0.f;
        if (lane < cnt) {
            uint2 ed = csr[base + lane];
            col_l = (int)ed.x;
            val_l = __uint_as_float(ed.y);
        }
        int j = 0;
        for (; j + 4 <= cnt; j += 4) {
            int   c0 = __shfl(col_l, j),     c1 = __shfl(col_l, j + 1);
            int   c2 = __shfl(col_l, j + 2), c3 = __shfl(col_l, j + 3);
            float v0 = __shfl(val_l, j),     v1 = __shfl(val_l, j + 1);
            float v2 = __shfl(val_l, j + 2), v3 = __shfl(val_l, j + 3);
            unsigned int x0 = Tu[c0 * 64 + lane];
            unsigned int x1 = Tu[c1 * 64 + lane];
            unsigned int x2 = Tu[c2 * 64 + lane];
            unsigned int x3 = Tu[c3 * 64 + lane];
            ax = fmaf(v0, bf_lo(x0), ax); ay = fmaf(v0, bf_hi(x0), ay);
            ax = fmaf(v1, bf_lo(x1), ax); ay = fmaf(v1, bf_hi(x1), ay);
            ax = fmaf(v2, bf_lo(x2), ax); ay = fmaf(v2, bf_hi(x2), ay);
            ax = fmaf(v3, bf_lo(x3), ax); ay = fmaf(v3, bf_hi(x3), ay);
        }
        for (; j < cnt; ++j) {
            int   c = __shfl(col_l, j);
            float v = __shfl(val_l, j);
            unsigned int x = Tu[c * 64 + lane];
            ax = fmaf(v, bf_lo(x), ax); ay = fmaf(v, bf_hi(x), ay);
        }
    }
    ax = fmaxf(ax, 0.f);
    ay = fmaxf(ay, 0.f);
    if constexpr (OUT_BF16) {
        unsigned int* o = (unsigned int*)outv;
        o[row * 64 + lane] = (unsigned int)f2bf(ax) | ((unsigned int)f2bf(ay) << 16);
    } else {
        float2* o = (float2*)((float*)outv + row * 128 + lane * 2);
        *o = make_float2(ax, ay);
    }
}

// ---------------- launch ----------------
extern "C" void kernel_launch(void* const* d_in, const int* in_sizes, int n_in,
                              void* d_out, int out_size, void* d_ws, size_t ws_size,
                              hipStream_t stream) {
    const float* X     = (const float*)d_in[0];  // [N,128] fp32
    const float* evals = (const float*)d_in[1];  // [E]
    const float* W0    = (const float*)d_in[2];  // [128,128]
    const float* W1    = (const float*)d_in[3];  // [128,128]
    const int* erows   = (const int*)d_in[4];    // [E]
    const int* ecols   = (const int*)d_in[5];    // [E]
    float* out = (float*)d_out;                  // [N,128] fp32

    char* ws = (char*)d_ws;
    size_t off = 0;
    auto carve = [&](size_t bytes) {
        char* p = ws + off;
        off += (bytes + 255) & ~(size_t)255;
        return p;
    };
    unsigned short* T = (unsigned short*)carve((size_t)N_NODES * F * 2);  // 25.6 MB bf16
    unsigned short* H = (unsigned short*)carve((size_t)N_NODES * F * 2);  // 25.6 MB bf16
    uint2* stage      = (uint2*)carve((size_t)N_EDGES * 8);               // 12.8 MB
    uint2* csr        = (uint2*)carve((size_t)N_EDGES * 8);               // 12.8 MB
    int* row_start    = (int*)carve((size_t)(N_NODES + 1) * 4);
    int* ghist        = (int*)carve((size_t)(NBUCKETS + 1) * 4);
    int* bucket_start = (int*)carve((size_t)(NBUCKETS + 1) * 4);
    int* bucket_cursor= (int*)carve((size_t)(NBUCKETS + 1) * 4);
    (void)ws_size; (void)in_sizes; (void)n_in; (void)out_size;

    // ---- CSR build (two-level counting sort) ----
    hipMemsetAsync(ghist, 0, (size_t)(NBUCKETS + 1) * 4, stream);
    bhist_kernel<<<ABLOCKS, 256, 0, stream>>>(erows, ghist);
    bscan_kernel<<<1, 256, 0, stream>>>(ghist, bucket_start, bucket_cursor);
    binA_kernel<<<ABLOCKS, 256, 0, stream>>>(erows, ecols, evals, bucket_cursor, stage);
    binB_kernel<<<NBUCKETS, 1024, 0, stream>>>(stage, bucket_start, csr, row_start);

    // ---- layer 0: H = relu(Ahat @ (X @ W0)) ----
    gemm128_kernel<false><<<N_NODES / TILE_R, 256, 0, stream>>>(X, W0, T);
    spmm_relu_kernel<true><<<N_NODES / 4, 256, 0, stream>>>(row_start, csr,
                                                            (const unsigned int*)T, H);

    // ---- layer 1: out = relu(Ahat @ (H @ W1)) ----
    gemm128_kernel<true><<<N_NODES / TILE_R, 256, 0, stream>>>(H, W1, T);
    spmm_relu_kernel<false><<<N_NODES / 4, 256, 0, stream>>>(row_start, csr,
                                                             (const unsigned int*)T, out);
}

// Round 4
// 220.537 us; speedup vs baseline: 2.8947x; 1.3056x over previous
//
#include <hip/hip_runtime.h>

#define N_NODES 100000
#define N_EDGES 1600000
#define F 128
#define M_PAD 100032          // 1563 blocks * 64 rows

#define BUCKET_BITS 9
#define BUCKET_SIZE 512
#define NBUCKETS ((N_NODES + BUCKET_SIZE - 1) / BUCKET_SIZE)  // 196
#define EPB_A 8192
#define ABLOCKS ((N_EDGES + EPB_A - 1) / EPB_A)               // 196

#define AS1 __attribute__((address_space(1)))
#define AS3 __attribute__((address_space(3)))

typedef __attribute__((ext_vector_type(8))) short short8;
typedef __attribute__((ext_vector_type(4))) float f32x4;

__device__ __forceinline__ float bf_lo(unsigned int u) { return __uint_as_float(u << 16); }
__device__ __forceinline__ float bf_hi(unsigned int u) { return __uint_as_float(u & 0xffff0000u); }
__device__ __forceinline__ unsigned short f2bf(float f) {
    unsigned int u = __float_as_uint(f);
    u += 0x7fffu + ((u >> 16) & 1u);   // round-to-nearest-even
    return (unsigned short)(u >> 16);
}
__device__ __forceinline__ void gload_lds16(const void* g, void* l) {
    __builtin_amdgcn_global_load_lds((const AS1 unsigned int*)g, (AS3 unsigned int*)l, 16, 0, 0);
}

// ---------------- CSR build: two-level counting sort ----------------

__global__ __launch_bounds__(256) void bhist_kernel(const int* __restrict__ rows,
                                                    int* __restrict__ ghist) {
    __shared__ int hist[NBUCKETS];
    int tid = threadIdx.x;
    int start = blockIdx.x * EPB_A;
    int cnt = min(EPB_A, N_EDGES - start);
    for (int i = tid; i < NBUCKETS; i += 256) hist[i] = 0;
    __syncthreads();
    for (int i = tid; i < cnt; i += 256) atomicAdd(&hist[rows[start + i] >> BUCKET_BITS], 1);
    __syncthreads();
    for (int i = tid; i < NBUCKETS; i += 256)
        if (hist[i]) atomicAdd(&ghist[i], hist[i]);
}

__global__ __launch_bounds__(256) void bscan_kernel(const int* __restrict__ ghist,
                                                    int* __restrict__ bucket_start,
                                                    int* __restrict__ bucket_cursor) {
    __shared__ int s[256];
    int t = threadIdx.x;
    int v = (t < NBUCKETS) ? ghist[t] : 0;
    s[t] = v;
    __syncthreads();
    for (int off = 1; off < 256; off <<= 1) {
        int x = (t >= off) ? s[t - off] : 0;
        __syncthreads();
        s[t] += x;
        __syncthreads();
    }
    if (t < NBUCKETS) {
        int ex = s[t] - v;
        bucket_start[t] = ex;
        bucket_cursor[t] = ex;
    }
    if (t == NBUCKETS - 1) bucket_start[NBUCKETS] = s[t];
}

__global__ __launch_bounds__(256) void binA_kernel(const int* __restrict__ rows,
                                                   const int* __restrict__ cols,
                                                   const float* __restrict__ vals,
                                                   int* __restrict__ bucket_cursor,
                                                   uint2* __restrict__ stage) {
    __shared__ int hist[NBUCKETS];
    __shared__ int base[NBUCKETS];
    int tid = threadIdx.x;
    int start = blockIdx.x * EPB_A;
    int cnt = min(EPB_A, N_EDGES - start);
    for (int i = tid; i < NBUCKETS; i += 256) hist[i] = 0;
    __syncthreads();
    for (int i = tid; i < cnt; i += 256) atomicAdd(&hist[rows[start + i] >> BUCKET_BITS], 1);
    __syncthreads();
    for (int i = tid; i < NBUCKETS; i += 256) {
        int h = hist[i];
        base[i] = h ? atomicAdd(&bucket_cursor[i], h) : 0;
        hist[i] = 0;
    }
    __syncthreads();
    for (int i = tid; i < cnt; i += 256) {
        int r = rows[start + i];
        int c = cols[start + i];
        unsigned vb = __float_as_uint(vals[start + i]);
        int b = r >> BUCKET_BITS;
        int p = base[b] + atomicAdd(&hist[b], 1);
        stage[p] = make_uint2(((unsigned)(r & (BUCKET_SIZE - 1)) << 17) | (unsigned)c, vb);
    }
}

__global__ __launch_bounds__(1024) void binB_kernel(const uint2* __restrict__ stage,
                                                    const int* __restrict__ bucket_start,
                                                    uint2* __restrict__ csr,
                                                    int* __restrict__ row_start) {
    __shared__ int hist[BUCKET_SIZE];
    __shared__ int scanv[BUCKET_SIZE];
    __shared__ int cur[BUCKET_SIZE];
    int b = blockIdx.x;
    int t = threadIdx.x;
    int s0 = bucket_start[b];
    int cnt = bucket_start[b + 1] - s0;
    if (t < BUCKET_SIZE) hist[t] = 0;
    __syncthreads();
    for (int i = t; i < cnt; i += 1024) atomicAdd(&hist[stage[s0 + i].x >> 17], 1);
    __syncthreads();
    if (t < BUCKET_SIZE) scanv[t] = hist[t];
    __syncthreads();
    for (int off = 1; off < BUCKET_SIZE; off <<= 1) {
        int x = 0;
        if (t < BUCKET_SIZE && t >= off) x = scanv[t - off];
        __syncthreads();
        if (t < BUCKET_SIZE) scanv[t] += x;
        __syncthreads();
    }
    if (t < BUCKET_SIZE) {
        int ex = s0 + scanv[t] - hist[t];
        cur[t] = ex;
        int row = (b << BUCKET_BITS) + t;
        if (row < N_NODES) row_start[row] = ex;
    }
    if (b == 0 && t == 0) row_start[N_NODES] = N_EDGES;
    __syncthreads();
    for (int i = t; i < cnt; i += 1024) {
        uint2 e = stage[s0 + i];
        int p = atomicAdd(&cur[e.x >> 17], 1);
        csr[p] = make_uint2(e.x & 0x1FFFFu, e.y);
    }
}

// ---------------- W transpose+swizzle pre-kernel ----------------
// Wt_swz[c][byte] = bf16(W[k][c]) with byte-in-row swizzled: 16o ^ ((c&7)<<4)
__global__ __launch_bounds__(256) void wtrans_kernel(const float* __restrict__ W,
                                                     unsigned short* __restrict__ Wt) {
    int t = threadIdx.x;
    int c = t & 127;
    int o0 = (t >> 7) * 8;
    for (int o = o0; o < o0 + 8; ++o) {
        short8 v;
#pragma unroll
        for (int e = 0; e < 8; ++e) v[e] = (short)f2bf(W[(o * 8 + e) * 128 + c]);
        *(short8*)((char*)Wt + c * 256 + ((o * 16) ^ ((c & 7) << 4))) = v;
    }
}

// ---------------- MFMA GEMM: T[node][feat] = A[node][:] @ W ----------------
// Computes D[feat][node] = Wt-frags (A-op) x Atile-frags (B-op), 64 nodes/block,
// wave w owns nodes w*16..+15, all 128 feats. LDS XOR-swizzled [outer][k] bf16.
template <bool IN_BF16>
__global__ __launch_bounds__(256) void mfma_gemm_kernel(const void* __restrict__ Av,
                                                        const unsigned short* __restrict__ Wt,
                                                        unsigned short* __restrict__ T) {
    __shared__ alignas(16) unsigned short wlds[128 * 128];  // 32 KB
    __shared__ alignas(16) unsigned short alds[64 * 128];   // 16 KB
    int tid = threadIdx.x;
    int w = tid >> 6, l = tid & 63;
    int q = l >> 4, c16 = l & 15;
    long r0 = (long)blockIdx.x * 64;

    // stage Wt (pre-swizzled in global -> linear copy), 8 x 1KB per wave
#pragma unroll
    for (int i = 0; i < 8; ++i) {
        int row = w * 32 + i * 4 + q;
        gload_lds16((const char*)Wt + row * 256 + c16 * 16,
                    (char*)wlds + (w * 8192 + i * 1024));
    }
    if constexpr (IN_BF16) {
        // H pre-swizzled in global -> linear copy, 4 x 1KB per wave
#pragma unroll
        for (int i = 0; i < 4; ++i) {
            int row = w * 16 + i * 4 + q;
            gload_lds16((const char*)Av + (r0 + row) * 256 + c16 * 16,
                        (char*)alds + (w * 4096 + i * 1024));
        }
    } else {
        // fp32 X: reg-stage, convert, swizzled ds_write_b128
        const float* X = (const float*)Av;
#pragma unroll
        for (int i = 0; i < 4; ++i) {
            int row = i * 16 + (tid >> 4);
            int oct = tid & 15;
            long rg = r0 + row;
            if (rg > N_NODES - 1) rg = N_NODES - 1;   // clamp: don't read past input
            const float4* xp = (const float4*)(X + rg * 128 + oct * 8);
            float4 a = xp[0], b = xp[1];
            short8 v;
            v[0] = (short)f2bf(a.x); v[1] = (short)f2bf(a.y);
            v[2] = (short)f2bf(a.z); v[3] = (short)f2bf(a.w);
            v[4] = (short)f2bf(b.x); v[5] = (short)f2bf(b.y);
            v[6] = (short)f2bf(b.z); v[7] = (short)f2bf(b.w);
            *(short8*)((char*)alds + row * 256 + ((oct * 16) ^ ((row & 7) << 4))) = v;
        }
    }
    __syncthreads();

    f32x4 acc[8] = {};
    int nrow = w * 16 + c16;                 // B-frag: node row in alds
    int nswz = (nrow & 7) << 4;
#pragma unroll
    for (int ks = 0; ks < 4; ++ks) {
        int kb = ks * 64 + q * 16;           // byte offset of this lane's k-octet
        short8 bfrag = *(const short8*)((const char*)alds + nrow * 256 + (kb ^ nswz));
#pragma unroll
        for (int fb = 0; fb < 8; ++fb) {
            int frow = fb * 16 + c16;        // A-frag: feat row in wlds
            short8 afrag = *(const short8*)((const char*)wlds + frow * 256 +
                                            (kb ^ ((frow & 7) << 4)));
            acc[fb] = __builtin_amdgcn_mfma_f32_16x16x32_bf16(afrag, bfrag, acc[fb], 0, 0, 0);
        }
    }

    // epilogue: lane holds feats fb*16 + q*4 + r for node r0 + w*16 + c16
    long node = r0 + w * 16 + c16;
#pragma unroll
    for (int fb = 0; fb < 8; ++fb) {
        uint2 o;
        o.x = (unsigned)f2bf(acc[fb][0]) | ((unsigned)f2bf(acc[fb][1]) << 16);
        o.y = (unsigned)f2bf(acc[fb][2]) | ((unsigned)f2bf(acc[fb][3]) << 16);
        *(uint2*)((char*)T + node * 256 + fb * 32 + q * 8) = o;
    }
}

// ---------------- SpMM (CSR packed, bf16 gather operand) + fused ReLU ----------------
// OUT_BF16 path writes H pre-swizzled (uint index: lane ^ ((row&7)<<2)) so the
// layer-1 GEMM can stage it linearly with global_load_lds.
template <bool OUT_BF16>
__global__ __launch_bounds__(256) void spmm_relu_kernel(const int* __restrict__ row_start,
                                                        const uint2* __restrict__ csr,
                                                        const unsigned int* __restrict__ Tu,
                                                        void* __restrict__ outv) {
    int wave = threadIdx.x >> 6;
    int lane = threadIdx.x & 63;
    int row = blockIdx.x * 4 + wave;
    int s = row_start[row];
    int e = row_start[row + 1];
    float ax = 0.f, ay = 0.f;
    for (int base = s; base < e; base += 64) {
        int cnt = min(64, e - base);
        int col_l = 0; float val_l = 0.f;
        if (lane < cnt) {
            uint2 ed = csr[base + lane];
            col_l = (int)ed.x;
            val_l = __uint_as_float(ed.y);
        }
        int j = 0;
        for (; j + 4 <= cnt; j += 4) {
            int   c0 = __shfl(col_l, j),     c1 = __shfl(col_l, j + 1);
            int   c2 = __shfl(col_l, j + 2), c3 = __shfl(col_l, j + 3);
            float v0 = __shfl(val_l, j),     v1 = __shfl(val_l, j + 1);
            float v2 = __shfl(val_l, j + 2), v3 = __shfl(val_l, j + 3);
            unsigned int x0 = Tu[c0 * 64 + lane];
            unsigned int x1 = Tu[c1 * 64 + lane];
            unsigned int x2 = Tu[c2 * 64 + lane];
            unsigned int x3 = Tu[c3 * 64 + lane];
            ax = fmaf(v0, bf_lo(x0), ax); ay = fmaf(v0, bf_hi(x0), ay);
            ax = fmaf(v1, bf_lo(x1), ax); ay = fmaf(v1, bf_hi(x1), ay);
            ax = fmaf(v2, bf_lo(x2), ax); ay = fmaf(v2, bf_hi(x2), ay);
            ax = fmaf(v3, bf_lo(x3), ax); ay = fmaf(v3, bf_hi(x3), ay);
        }
        for (; j < cnt; ++j) {
            int   c = __shfl(col_l, j);
            float v = __shfl(val_l, j);
            unsigned int x = Tu[c * 64 + lane];
            ax = fmaf(v, bf_lo(x), ax); ay = fmaf(v, bf_hi(x), ay);
        }
    }
    ax = fmaxf(ax, 0.f);
    ay = fmaxf(ay, 0.f);
    if constexpr (OUT_BF16) {
        unsigned int* o = (unsigned int*)outv;
        o[row * 64 + (lane ^ ((row & 7) << 2))] =
            (unsigned int)f2bf(ax) | ((unsigned int)f2bf(ay) << 16);
    } else {
        float2* o = (float2*)((float*)outv + row * 128 + lane * 2);
        *o = make_float2(ax, ay);
    }
}

// ---------------- launch ----------------
extern "C" void kernel_launch(void* const* d_in, const int* in_sizes, int n_in,
                              void* d_out, int out_size, void* d_ws, size_t ws_size,
                              hipStream_t stream) {
    const float* X     = (const float*)d_in[0];  // [N,128] fp32
    const float* evals = (const float*)d_in[1];  // [E]
    const float* W0    = (const float*)d_in[2];  // [128,128]
    const float* W1    = (const float*)d_in[3];  // [128,128]
    const int* erows   = (const int*)d_in[4];    // [E]
    const int* ecols   = (const int*)d_in[5];    // [E]
    float* out = (float*)d_out;                  // [N,128] fp32

    char* ws = (char*)d_ws;
    size_t off = 0;
    auto carve = [&](size_t bytes) {
        char* p = ws + off;
        off += (bytes + 255) & ~(size_t)255;
        return p;
    };
    unsigned short* T   = (unsigned short*)carve((size_t)M_PAD * F * 2);  // 25.6 MB
    unsigned short* H   = (unsigned short*)carve((size_t)M_PAD * F * 2);  // 25.6 MB
    unsigned short* Wt0 = (unsigned short*)carve(128 * 128 * 2);
    unsigned short* Wt1 = (unsigned short*)carve(128 * 128 * 2);
    uint2* stage        = (uint2*)carve((size_t)N_EDGES * 8);             // 12.8 MB
    uint2* csr          = (uint2*)carve((size_t)N_EDGES * 8);             // 12.8 MB
    int* row_start      = (int*)carve((size_t)(N_NODES + 1) * 4);
    int* ghist          = (int*)carve((size_t)(NBUCKETS + 1) * 4);
    int* bucket_start   = (int*)carve((size_t)(NBUCKETS + 1) * 4);
    int* bucket_cursor  = (int*)carve((size_t)(NBUCKETS + 1) * 4);
    (void)ws_size; (void)in_sizes; (void)n_in; (void)out_size;

    // ---- weight transpose (tiny) ----
    wtrans_kernel<<<1, 256, 0, stream>>>(W0, Wt0);
    wtrans_kernel<<<1, 256, 0, stream>>>(W1, Wt1);

    // ---- CSR build (two-level counting sort) ----
    hipMemsetAsync(ghist, 0, (size_t)(NBUCKETS + 1) * 4, stream);
    bhist_kernel<<<ABLOCKS, 256, 0, stream>>>(erows, ghist);
    bscan_kernel<<<1, 256, 0, stream>>>(ghist, bucket_start, bucket_cursor);
    binA_kernel<<<ABLOCKS, 256, 0, stream>>>(erows, ecols, evals, bucket_cursor, stage);
    binB_kernel<<<NBUCKETS, 1024, 0, stream>>>(stage, bucket_start, csr, row_start);

    int gemm_grid = M_PAD / 64;  // 1563

    // ---- layer 0: H = relu(Ahat @ (X @ W0)) ----
    mfma_gemm_kernel<false><<<gemm_grid, 256, 0, stream>>>(X, Wt0, T);
    spmm_relu_kernel<true><<<N_NODES / 4, 256, 0, stream>>>(row_start, csr,
                                                            (const unsigned int*)T, H);

    // ---- layer 1: out = relu(Ahat @ (H @ W1)) ----
    mfma_gemm_kernel<true><<<gemm_grid, 256, 0, stream>>>(H, Wt1, T);
    spmm_relu_kernel<false><<<N_NODES / 4, 256, 0, stream>>>(row_start, csr,
                                                             (const unsigned int*)T, out);
}